// Round 10
// baseline (4096.624 us; speedup 1.0000x reference)
//
#include <hip/hip_runtime.h>
#include <hip/hip_bf16.h>

#define HH 32
#define NN 32
#define LL 24000
#define BB 128
#define CHUNK 32
#define NCHUNK (LL / CHUNK) // 750

// exact-ish gelu: 0.5*v*(1+erf(v/sqrt2)), erf via Abramowitz-Stegun 7.1.26 (abs err ~1.5e-7)
__device__ __forceinline__ float fast_gelu(float v) {
    float z = fabsf(v) * 0.7071067811865476f;
    float t = 1.0f / (1.0f + 0.3275911f * z);
    float poly = t * (0.254829592f +
               t * (-0.284496736f +
               t * (1.421413741f +
               t * (-1.453152027f +
               t * 1.061405429f))));
    float e = 1.0f - poly * __expf(-z * z);
    e = copysignf(e, v);
    return 0.5f * v * (1.0f + e);
}

// ds_swizzle pattern must be a literal constant at the call site -> macros.
#define SWZ(v, imm) __int_as_float(__builtin_amdgcn_ds_swizzle(__float_as_int(v), (imm)))

struct ScanParams { float wr, wi, c2r, c2i; };

// Discretized S4D per-(h,n) recurrence params: w = exp(dt*A),
// c2 = 2*C*B*(w-1)/A (real/imag), so y_t = Re(c2 . s_t) with s_t = w s_{t-1} + u_t.
__device__ __forceinline__ ScanParams prep_params(
    const float* __restrict__ log_dt, const float* __restrict__ log_A_real,
    const float* __restrict__ A_imag, const float* __restrict__ B_re,
    const float* __restrict__ B_im, const float* __restrict__ C_re,
    const float* __restrict__ C_im, int h, int n)
{
    const int hn = h * NN + n;
    float dt = __expf(log_dt[h]);
    float Are = -__expf(log_A_real[hn]);
    float Aim = A_imag[hn];
    float em = __expf(dt * Are);
    float wr = em * cosf(dt * Aim);
    float wi = em * sinf(dt * Aim);
    float Br = B_re[hn], Bi = B_im[hn];
    float Cr = C_re[hn], Ci = C_im[hn];
    float CBr = Cr * Br - Ci * Bi;
    float CBi = Cr * Bi + Ci * Br;
    float e1r = wr - 1.0f, e1i = wi;
    float numr = CBr * e1r - CBi * e1i;
    float numi = CBr * e1i + CBi * e1r;
    float inv = 1.0f / (Are * Are + Aim * Aim);
    ScanParams P;
    P.wr = wr; P.wi = wi;
    P.c2r = 2.0f * (numr * Are + numi * Aim) * inv;
    P.c2i = 2.0f * (numi * Are - numr * Aim) * inv;
    return P;
}

// One 32-step chunk of the diagonal SSM for a 32-lane group (lane = state n).
// Input: u = this lane's timestep input (lane t role). State (sr,si) carried.
// Returns, in lane t, sum_n y-contribution at step t (reduce-scatter).
__device__ __forceinline__ float ssm_chunk(float u, int lane, const ScanParams P,
                                           float& sr, float& si)
{
    float xs[CHUNK];
#define BC(t) xs[t] = SWZ(u, ((t) << 5));
#define B8(b0) BC(b0) BC((b0)+1) BC((b0)+2) BC((b0)+3) BC((b0)+4) BC((b0)+5) BC((b0)+6) BC((b0)+7)
    B8(0) B8(8) B8(16) B8(24)
#undef B8
#undef BC

    float p[CHUNK];
#pragma unroll
    for (int t = 0; t < CHUNK; ++t) {
        float t1 = __fmaf_rn(-P.wi, si, xs[t]);
        float nsr = __fmaf_rn(P.wr, sr, t1);
        float nsi = __fmaf_rn(P.wi, sr, P.wr * si);
        sr = nsr;
        si = nsi;
        p[t] = __fmaf_rn(P.c2r, sr, -(P.c2i * si));
    }

    // xor-butterfly reduce-scatter: lane i ends with sum_n p_n[i]
#define BFLY(d, IMM)                                                  \
    {                                                                 \
        bool up = (lane & (d)) != 0;                                  \
        _Pragma("unroll")                                             \
        for (int j = 0; j < (d); ++j) {                               \
            float send = up ? p[j] : p[j + (d)];                      \
            float recv = SWZ(send, (IMM));                            \
            float keep = up ? p[j + (d)] : p[j];                      \
            p[j] = keep + recv;                                       \
        }                                                             \
    }
    BFLY(16, (16 << 10) | 0x1f)
    BFLY(8,  (8  << 10) | 0x1f)
    BFLY(4,  (4  << 10) | 0x1f)
    BFLY(2,  (2  << 10) | 0x1f)
    BFLY(1,  (1  << 10) | 0x1f)
#undef BFLY
    return p[0];
}

// ---------------- Path A: 4-kernel pipeline (needs 393MB workspace) ----------

template <int LAYER>
__global__ __launch_bounds__(256) void scan_kernel(
    const float* in, const float* __restrict__ W1, const float* __restrict__ b1,
    const float* __restrict__ log_dt, const float* __restrict__ log_A_real,
    const float* __restrict__ A_imag, const float* __restrict__ B_re,
    const float* __restrict__ B_im, const float* __restrict__ C_re,
    const float* __restrict__ C_im, const float* __restrict__ Dp,
    float* out)
{
    const int lane = threadIdx.x & 31;
    const int seq = blockIdx.x * 8 + (threadIdx.x >> 5);
    const int b = seq >> 5;
    const int h = seq & 31;

    const ScanParams P = prep_params(log_dt, log_A_real, A_imag, B_re, B_im, C_re, C_im, h, lane);
    float Dh = Dp[h];
    float w1h = 0.f, b1h = 0.f;
    if constexpr (LAYER == 1) { w1h = W1[h]; b1h = b1[h]; }

    const float* src;
    if constexpr (LAYER == 1) src = in + (size_t)b * LL;
    else                      src = in + ((size_t)b * HH + h) * LL;
    float* dst = out + ((size_t)b * HH + h) * LL;

    float sr = 0.f, si = 0.f;
    for (int c = 0; c < NCHUNK; ++c) {
        const int t0 = c * CHUNK;
        float v = src[t0 + lane];
        float u;
        if constexpr (LAYER == 1) {
            float xl = 6.020599913f * __log2f(fmaxf(fabsf(v), 1e-4f));
            u = fast_gelu(__fmaf_rn(xl, w1h, b1h));
        } else {
            u = v;
        }
        float p0 = ssm_chunk(u, lane, P, sr, si);
        dst[t0 + lane] = fast_gelu(__fmaf_rn(Dh, u, p0));
    }
}

__global__ __launch_bounds__(256) void mix_kernel(
    const float* g1, const float* __restrict__ W2,
    const float* __restrict__ b2, float* u2)
{
    const int b = blockIdx.y;
    const int l = blockIdx.x * 256 + threadIdx.x;
    if (l >= LL) return;
    float r[HH];
#pragma unroll
    for (int h2 = 0; h2 < HH; ++h2)
        r[h2] = g1[((size_t)b * HH + h2) * LL + l];
#pragma unroll
    for (int h = 0; h < HH; ++h) {
        float acc = b2[h];
#pragma unroll
        for (int h2 = 0; h2 < HH; ++h2)
            acc = __fmaf_rn(r[h2], W2[h2 * HH + h], acc);
        u2[((size_t)b * HH + h) * LL + l] = fast_gelu(acc);
    }
}

__global__ __launch_bounds__(256) void final_kernel(
    const float* __restrict__ g2, const float* __restrict__ W3,
    const float* __restrict__ b3, float* __restrict__ outp)
{
    const int b = blockIdx.y;
    const int l = blockIdx.x * 256 + threadIdx.x;
    if (l >= LL) return;
    float acc = b3[0];
#pragma unroll
    for (int h = 0; h < HH; ++h)
        acc = __fmaf_rn(g2[((size_t)b * HH + h) * LL + l], W3[h], acc);
    outp[(size_t)b * LL + l] = exp2f(acc * 0.16609640474436813f);
}

// ---------------- Path B: fused per-batch kernel (zero workspace) ------------
// Block b: 1024 threads = 32 groups of 32 lanes. group = h; lane = n (scan) / t (pointwise).
// Per chunk: encoder -> SSM1 -> ldsA -> barrier -> mix (W2 in LDS) -> SSM2 ->
// ldsB -> barrier -> group0 decoder + store. Two barriers/chunk; A/B buffers
// make the schedule race-free across waves.
__global__ __launch_bounds__(1024) void fused_kernel(
    const float* __restrict__ x,
    const float* __restrict__ W1, const float* __restrict__ b1,
    const float* __restrict__ W2, const float* __restrict__ b2,
    const float* __restrict__ W3, const float* __restrict__ b3,
    const float* __restrict__ log_dt1, const float* __restrict__ log_A_real1,
    const float* __restrict__ A_imag1, const float* __restrict__ B_re1,
    const float* __restrict__ B_im1, const float* __restrict__ C_re1,
    const float* __restrict__ C_im1, const float* __restrict__ D1,
    const float* __restrict__ log_dt2, const float* __restrict__ log_A_real2,
    const float* __restrict__ A_imag2, const float* __restrict__ B_re2,
    const float* __restrict__ B_im2, const float* __restrict__ C_re2,
    const float* __restrict__ C_im2, const float* __restrict__ D2,
    float* __restrict__ outp)
{
    __shared__ float ldsA[HH * CHUNK];
    __shared__ float ldsB[HH * CHUNK];
    __shared__ float ldsW2[HH * HH];

    const int tid = threadIdx.x;
    const int lane = tid & 31;
    const int h = tid >> 5;
    const int b = blockIdx.x;

    ldsW2[tid] = W2[tid]; // 1024 == HH*HH; ordered before first read by bar1 of chunk 0

    const ScanParams P1 = prep_params(log_dt1, log_A_real1, A_imag1, B_re1, B_im1, C_re1, C_im1, h, lane);
    const ScanParams P2 = prep_params(log_dt2, log_A_real2, A_imag2, B_re2, B_im2, C_re2, C_im2, h, lane);
    const float w1h = W1[h], b1h = b1[h];
    const float Dh1 = D1[h], Dh2 = D2[h];
    const float b2h = b2[h];
    const float b30 = b3[0];
    float w3r[HH];
#pragma unroll
    for (int hh = 0; hh < HH; ++hh) w3r[hh] = W3[hh];

    const float* src = x + (size_t)b * LL;
    float* dst = outp + (size_t)b * LL;

    float sr1 = 0.f, si1 = 0.f, sr2 = 0.f, si2 = 0.f;

    for (int c = 0; c < NCHUNK; ++c) {
        const int t0 = c * CHUNK;
        // encoder: this lane plays timestep t = lane
        float v = src[t0 + lane];
        float xl = 6.020599913f * __log2f(fmaxf(fabsf(v), 1e-4f));
        float u1 = fast_gelu(__fmaf_rn(xl, w1h, b1h));
        // SSM1
        float p0 = ssm_chunk(u1, lane, P1, sr1, si1);
        float g1v = fast_gelu(__fmaf_rn(Dh1, u1, p0));
        ldsA[(h << 5) | lane] = g1v;
        __syncthreads(); // bar1: ldsA (and ldsW2 on c==0) visible
        // mix: u2[h][t] = gelu(b2[h] + sum_h' g1[h'][t] * W2[h'][h])
        float acc = b2h;
#pragma unroll
        for (int h2 = 0; h2 < HH; ++h2)
            acc = __fmaf_rn(ldsA[(h2 << 5) | lane], ldsW2[(h2 << 5) | h], acc);
        float u2 = fast_gelu(acc);
        // SSM2
        float q0 = ssm_chunk(u2, lane, P2, sr2, si2);
        float g2v = fast_gelu(__fmaf_rn(Dh2, u2, q0));
        ldsB[(h << 5) | lane] = g2v;
        __syncthreads(); // bar2: ldsB visible; all ldsA reads done
        if (h == 0) {
            float a = b30;
#pragma unroll
            for (int hh = 0; hh < HH; ++hh)
                a = __fmaf_rn(ldsB[(hh << 5) | lane], w3r[hh], a);
            dst[t0 + lane] = exp2f(a * 0.16609640474436813f);
        }
        // next chunk's ldsA writes are ordered after bar2; its ldsB writes are
        // ordered after next bar1, which group0 reaches only after the reads above.
    }
}

extern "C" void kernel_launch(void* const* d_in, const int* in_sizes, int n_in,
                              void* d_out, int out_size, void* d_ws, size_t ws_size,
                              hipStream_t stream)
{
    const float* x  = (const float*)d_in[0];
    const float* W1 = (const float*)d_in[1];
    const float* b1 = (const float*)d_in[2];
    const float* W2 = (const float*)d_in[3];
    const float* b2 = (const float*)d_in[4];
    const float* W3 = (const float*)d_in[5];
    const float* b3 = (const float*)d_in[6];
    const float* p1[8];
    const float* p2[8];
    for (int i = 0; i < 8; ++i) p1[i] = (const float*)d_in[7 + i];
    for (int i = 0; i < 8; ++i) p2[i] = (const float*)d_in[15 + i];
    float* outp = (float*)d_out;

    const size_t need = (size_t)BB * HH * LL * sizeof(float); // 393,216,000 B

    if (ws_size >= need) {
        // Path A: full-chip 4-kernel pipeline using d_ws as one [B,H,L] buffer.
        float* buf = (float*)d_ws;
        dim3 sgrid(512), sblk(256);
        dim3 egrid((LL + 255) / 256, BB), eblk(256);
        scan_kernel<1><<<sgrid, sblk, 0, stream>>>(
            x, W1, b1, p1[0], p1[1], p1[2], p1[3], p1[4], p1[5], p1[6], p1[7], buf);
        mix_kernel<<<egrid, eblk, 0, stream>>>(buf, W2, b2, buf);
        scan_kernel<2><<<sgrid, sblk, 0, stream>>>(
            buf, nullptr, nullptr, p2[0], p2[1], p2[2], p2[3], p2[4], p2[5], p2[6], p2[7], buf);
        final_kernel<<<egrid, eblk, 0, stream>>>(buf, W3, b3, outp);
    } else {
        // Path B: zero-workspace fused kernel, one block per batch element.
        fused_kernel<<<dim3(BB), dim3(1024), 0, stream>>>(
            x, W1, b1, W2, b2, W3, b3,
            p1[0], p1[1], p1[2], p1[3], p1[4], p1[5], p1[6], p1[7],
            p2[0], p2[1], p2[2], p2[3], p2[4], p2[5], p2[6], p2[7],
            outp);
    }
}

// Round 14
// 3831.593 us; speedup vs baseline: 1.0692x; 1.0692x over previous
//
#include <hip/hip_runtime.h>
#include <hip/hip_bf16.h>

#define HH 32
#define NN 32
#define LL 24000
#define BB 128
#define CHUNK 32
#define NCHUNK (LL / CHUNK) // 750

// exact-ish gelu: 0.5*v*(1+erf(v/sqrt2)), erf via Abramowitz-Stegun 7.1.26 (abs err ~1.5e-7)
__device__ __forceinline__ float fast_gelu(float v) {
    float z = fabsf(v) * 0.7071067811865476f;
    float t = 1.0f / (1.0f + 0.3275911f * z);
    float poly = t * (0.254829592f +
               t * (-0.284496736f +
               t * (1.421413741f +
               t * (-1.453152027f +
               t * 1.061405429f))));
    float e = 1.0f - poly * __expf(-z * z);
    e = copysignf(e, v);
    return 0.5f * v * (1.0f + e);
}

// ds_swizzle pattern must be a literal constant at the call site -> macros.
#define SWZ(v, imm) __int_as_float(__builtin_amdgcn_ds_swizzle(__float_as_int(v), (imm)))

struct ScanParams { float wr, wi, c2r, c2i; };

// Discretized S4D per-(h,n) recurrence params: w = exp(dt*A),
// c2 = 2*C*B*(w-1)/A (real/imag), so y_t = Re(c2 . s_t) with s_t = w s_{t-1} + u_t.
__device__ __forceinline__ ScanParams prep_params(
    const float* __restrict__ log_dt, const float* __restrict__ log_A_real,
    const float* __restrict__ A_imag, const float* __restrict__ B_re,
    const float* __restrict__ B_im, const float* __restrict__ C_re,
    const float* __restrict__ C_im, int h, int n)
{
    const int hn = h * NN + n;
    float dt = __expf(log_dt[h]);
    float Are = -__expf(log_A_real[hn]);
    float Aim = A_imag[hn];
    float em = __expf(dt * Are);
    float wr = em * cosf(dt * Aim);
    float wi = em * sinf(dt * Aim);
    float Br = B_re[hn], Bi = B_im[hn];
    float Cr = C_re[hn], Ci = C_im[hn];
    float CBr = Cr * Br - Ci * Bi;
    float CBi = Cr * Bi + Ci * Br;
    float e1r = wr - 1.0f, e1i = wi;
    float numr = CBr * e1r - CBi * e1i;
    float numi = CBr * e1i + CBi * e1r;
    float inv = 1.0f / (Are * Are + Aim * Aim);
    ScanParams P;
    P.wr = wr; P.wi = wi;
    P.c2r = 2.0f * (numr * Are + numi * Aim) * inv;
    P.c2i = 2.0f * (numi * Are - numr * Aim) * inv;
    return P;
}

// One 32-step chunk of the diagonal SSM for a 32-lane group (lane = state n).
// u = this lane's timestep input (lane t role). State (sr,si) carried.
// ldsRow: 32-float, 16B-aligned scratch row private to this group; used to
// broadcast the 32 chunk inputs (1 ds_write + 8 uniform ds_read_b128 instead
// of 32 ds_swizzle: DS-pipe is the bottleneck). Wave-lockstep makes the
// write->read safe without a barrier (same wave produces and consumes).
// Returns, in lane t, sum_n y-contribution at step t (reduce-scatter).
__device__ __forceinline__ float ssm_chunk(float u, int lane, const ScanParams P,
                                           float& sr, float& si,
                                           float* __restrict__ ldsRow)
{
    ldsRow[lane] = u;
    float xs[CHUNK];
    const float4* q4 = (const float4*)ldsRow;
#pragma unroll
    for (int k = 0; k < 8; ++k) {
        float4 v4 = q4[k];               // uniform address -> LDS broadcast
        xs[4 * k + 0] = v4.x;
        xs[4 * k + 1] = v4.y;
        xs[4 * k + 2] = v4.z;
        xs[4 * k + 3] = v4.w;
    }

    float p[CHUNK];
#pragma unroll
    for (int t = 0; t < CHUNK; ++t) {
        float t1 = __fmaf_rn(-P.wi, si, xs[t]);
        float nsr = __fmaf_rn(P.wr, sr, t1);
        float nsi = __fmaf_rn(P.wi, sr, P.wr * si);
        sr = nsr;
        si = nsi;
        p[t] = __fmaf_rn(P.c2r, sr, -(P.c2i * si));
    }

    // xor-butterfly reduce-scatter: lane i ends with sum_n p_n[i]
#define BFLY(d, IMM)                                                  \
    {                                                                 \
        bool up = (lane & (d)) != 0;                                  \
        _Pragma("unroll")                                             \
        for (int j = 0; j < (d); ++j) {                               \
            float send = up ? p[j] : p[j + (d)];                      \
            float recv = SWZ(send, (IMM));                            \
            float keep = up ? p[j + (d)] : p[j];                      \
            p[j] = keep + recv;                                       \
        }                                                             \
    }
    BFLY(16, (16 << 10) | 0x1f)
    BFLY(8,  (8  << 10) | 0x1f)
    BFLY(4,  (4  << 10) | 0x1f)
    BFLY(2,  (2  << 10) | 0x1f)
    BFLY(1,  (1  << 10) | 0x1f)
#undef BFLY
    return p[0];
}

// ---------------- Path A: 4-kernel pipeline over a batch chunk ---------------
// Grid: 4*bchunk blocks x 256 threads = bchunk*32 sequences (8 groups/block).

template <int LAYER>
__global__ __launch_bounds__(256) void scan_kernel(
    const float* in, const float* __restrict__ W1, const float* __restrict__ b1,
    const float* __restrict__ log_dt, const float* __restrict__ log_A_real,
    const float* __restrict__ A_imag, const float* __restrict__ B_re,
    const float* __restrict__ B_im, const float* __restrict__ C_re,
    const float* __restrict__ C_im, const float* __restrict__ Dp,
    float* out)
{
    __shared__ __align__(16) float ldsU[8][CHUNK];
    const int lane = threadIdx.x & 31;
    const int g = threadIdx.x >> 5;
    const int seq = blockIdx.x * 8 + g;
    const int b = seq >> 5;   // batch index within this chunk
    const int h = seq & 31;

    const ScanParams P = prep_params(log_dt, log_A_real, A_imag, B_re, B_im, C_re, C_im, h, lane);
    float Dh = Dp[h];
    float w1h = 0.f, b1h = 0.f;
    if constexpr (LAYER == 1) { w1h = W1[h]; b1h = b1[h]; }

    const float* src;
    if constexpr (LAYER == 1) src = in + (size_t)b * LL;
    else                      src = in + ((size_t)b * HH + h) * LL;
    float* dst = out + ((size_t)b * HH + h) * LL;

    float sr = 0.f, si = 0.f;
    for (int c = 0; c < NCHUNK; ++c) {
        const int t0 = c * CHUNK;
        float v = src[t0 + lane];
        float u;
        if constexpr (LAYER == 1) {
            float xl = 6.020599913f * __log2f(fmaxf(fabsf(v), 1e-4f));
            u = fast_gelu(__fmaf_rn(xl, w1h, b1h));
        } else {
            u = v;
        }
        float p0 = ssm_chunk(u, lane, P, sr, si, ldsU[g]);
        dst[t0 + lane] = fast_gelu(__fmaf_rn(Dh, u, p0));
    }
}

__global__ __launch_bounds__(256) void mix_kernel(
    const float* g1, const float* __restrict__ W2,
    const float* __restrict__ b2, float* u2)
{
    const int b = blockIdx.y;
    const int l = blockIdx.x * 256 + threadIdx.x;
    if (l >= LL) return;
    float r[HH];
#pragma unroll
    for (int h2 = 0; h2 < HH; ++h2)
        r[h2] = g1[((size_t)b * HH + h2) * LL + l];
#pragma unroll
    for (int h = 0; h < HH; ++h) {
        float acc = b2[h];
#pragma unroll
        for (int h2 = 0; h2 < HH; ++h2)
            acc = __fmaf_rn(r[h2], W2[h2 * HH + h], acc);
        u2[((size_t)b * HH + h) * LL + l] = fast_gelu(acc);
    }
}

__global__ __launch_bounds__(256) void final_kernel(
    const float* __restrict__ g2, const float* __restrict__ W3,
    const float* __restrict__ b3, float* __restrict__ outp)
{
    const int b = blockIdx.y;
    const int l = blockIdx.x * 256 + threadIdx.x;
    if (l >= LL) return;
    float acc = b3[0];
#pragma unroll
    for (int h = 0; h < HH; ++h)
        acc = __fmaf_rn(g2[((size_t)b * HH + h) * LL + l], W3[h], acc);
    outp[(size_t)b * LL + l] = exp2f(acc * 0.16609640474436813f);
}

// ---------------- Path B: fused per-batch kernel (zero workspace) ------------
__global__ __launch_bounds__(1024) void fused_kernel(
    const float* __restrict__ x,
    const float* __restrict__ W1, const float* __restrict__ b1,
    const float* __restrict__ W2, const float* __restrict__ b2,
    const float* __restrict__ W3, const float* __restrict__ b3,
    const float* __restrict__ log_dt1, const float* __restrict__ log_A_real1,
    const float* __restrict__ A_imag1, const float* __restrict__ B_re1,
    const float* __restrict__ B_im1, const float* __restrict__ C_re1,
    const float* __restrict__ C_im1, const float* __restrict__ D1,
    const float* __restrict__ log_dt2, const float* __restrict__ log_A_real2,
    const float* __restrict__ A_imag2, const float* __restrict__ B_re2,
    const float* __restrict__ B_im2, const float* __restrict__ C_re2,
    const float* __restrict__ C_im2, const float* __restrict__ D2,
    float* __restrict__ outp)
{
    __shared__ float ldsA[HH * CHUNK];
    __shared__ float ldsB[HH * CHUNK];
    __shared__ float ldsW2[HH * HH];
    __shared__ __align__(16) float ldsU[HH][CHUNK];

    const int tid = threadIdx.x;
    const int lane = tid & 31;
    const int h = tid >> 5;
    const int b = blockIdx.x;

    ldsW2[tid] = W2[tid]; // 1024 == HH*HH; ordered before first read by bar1 of chunk 0

    const ScanParams P1 = prep_params(log_dt1, log_A_real1, A_imag1, B_re1, B_im1, C_re1, C_im1, h, lane);
    const ScanParams P2 = prep_params(log_dt2, log_A_real2, A_imag2, B_re2, B_im2, C_re2, C_im2, h, lane);
    const float w1h = W1[h], b1h = b1[h];
    const float Dh1 = D1[h], Dh2 = D2[h];
    const float b2h = b2[h];
    const float b30 = b3[0];
    float w3r[HH];
#pragma unroll
    for (int hh = 0; hh < HH; ++hh) w3r[hh] = W3[hh];

    const float* src = x + (size_t)b * LL;
    float* dst = outp + (size_t)b * LL;

    float sr1 = 0.f, si1 = 0.f, sr2 = 0.f, si2 = 0.f;

    for (int c = 0; c < NCHUNK; ++c) {
        const int t0 = c * CHUNK;
        // encoder: this lane plays timestep t = lane
        float v = src[t0 + lane];
        float xl = 6.020599913f * __log2f(fmaxf(fabsf(v), 1e-4f));
        float u1 = fast_gelu(__fmaf_rn(xl, w1h, b1h));
        // SSM1
        float p0 = ssm_chunk(u1, lane, P1, sr1, si1, ldsU[h]);
        float g1v = fast_gelu(__fmaf_rn(Dh1, u1, p0));
        ldsA[(h << 5) | lane] = g1v;
        __syncthreads(); // bar1: ldsA (and ldsW2 on c==0) visible
        // mix: u2[h][t] = gelu(b2[h] + sum_h' g1[h'][t] * W2[h'][h])
        float acc = b2h;
#pragma unroll
        for (int h2 = 0; h2 < HH; ++h2)
            acc = __fmaf_rn(ldsA[(h2 << 5) | lane], ldsW2[(h2 << 5) | h], acc);
        float u2 = fast_gelu(acc);
        // SSM2
        float q0 = ssm_chunk(u2, lane, P2, sr2, si2, ldsU[h]);
        float g2v = fast_gelu(__fmaf_rn(Dh2, u2, q0));
        ldsB[(h << 5) | lane] = g2v;
        __syncthreads(); // bar2: ldsB visible; all ldsA reads done
        if (h == 0) {
            float a = b30;
#pragma unroll
            for (int hh = 0; hh < HH; ++hh)
                a = __fmaf_rn(ldsB[(hh << 5) | lane], w3r[hh], a);
            dst[t0 + lane] = exp2f(a * 0.16609640474436813f);
        }
    }
}

extern "C" void kernel_launch(void* const* d_in, const int* in_sizes, int n_in,
                              void* d_out, int out_size, void* d_ws, size_t ws_size,
                              hipStream_t stream)
{
    const float* x  = (const float*)d_in[0];
    const float* W1 = (const float*)d_in[1];
    const float* b1 = (const float*)d_in[2];
    const float* W2 = (const float*)d_in[3];
    const float* b2 = (const float*)d_in[4];
    const float* W3 = (const float*)d_in[5];
    const float* b3 = (const float*)d_in[6];
    const float* p1[8];
    const float* p2[8];
    for (int i = 0; i < 8; ++i) p1[i] = (const float*)d_in[7 + i];
    for (int i = 0; i < 8; ++i) p2[i] = (const float*)d_in[15 + i];
    float* outp = (float*)d_out;

    const size_t per_batch = (size_t)HH * LL * sizeof(float); // 3,072,000 B

    int bchunk = 0;
    if      (ws_size >= 128 * per_batch) bchunk = 128; // 393 MB: single sweep
    else if (ws_size >=  64 * per_batch) bchunk = 64;  // 196 MB: two sweeps
    else if (ws_size >=  32 * per_batch) bchunk = 32;  // 98 MB: four sweeps

    if (bchunk > 0) {
        // Path A: 4-kernel pipeline, batch-chunked to fit workspace. fp32-exact.
        float* buf = (float*)d_ws; // [bchunk, H, L] f32, reused in place per sweep
        for (int b0 = 0; b0 < BB; b0 += bchunk) {
            dim3 sgrid(4 * bchunk), sblk(256);
            dim3 egrid((LL + 255) / 256, bchunk), eblk(256);
            scan_kernel<1><<<sgrid, sblk, 0, stream>>>(
                x + (size_t)b0 * LL, W1, b1,
                p1[0], p1[1], p1[2], p1[3], p1[4], p1[5], p1[6], p1[7], buf);
            mix_kernel<<<egrid, eblk, 0, stream>>>(buf, W2, b2, buf);
            scan_kernel<2><<<sgrid, sblk, 0, stream>>>(
                buf, nullptr, nullptr,
                p2[0], p2[1], p2[2], p2[3], p2[4], p2[5], p2[6], p2[7], buf);
            final_kernel<<<egrid, eblk, 0, stream>>>(
                buf, W3, b3, outp + (size_t)b0 * LL);
        }
    } else {
        // Path B: zero-workspace fused kernel, one block per batch element.
        fused_kernel<<<dim3(BB), dim3(1024), 0, stream>>>(
            x, W1, b1, W2, b2, W3, b3,
            p1[0], p1[1], p1[2], p1[3], p1[4], p1[5], p1[6], p1[7],
            p2[0], p2[1], p2[2], p2[3], p2[4], p2[5], p2[6], p2[7],
            outp);
    }
}

// Round 15
// 2493.760 us; speedup vs baseline: 1.6428x; 1.5365x over previous
//
#include <hip/hip_runtime.h>
#include <hip/hip_bf16.h>

#define HH 32
#define NN 32
#define LL 24000
#define BB 128
#define CHUNK 32
#define NCHUNK (LL / CHUNK)        // 750
#define NSEG 6
#define SEGCHUNKS (NCHUNK / NSEG)  // 125
#define SEGLEN (SEGCHUNKS * CHUNK) // 4000

// exact-ish gelu: 0.5*v*(1+erf(v/sqrt2)), erf via Abramowitz-Stegun 7.1.26 (abs err ~1.5e-7)
__device__ __forceinline__ float fast_gelu(float v) {
    float z = fabsf(v) * 0.7071067811865476f;
    float t = 1.0f / (1.0f + 0.3275911f * z);
    float poly = t * (0.254829592f +
               t * (-0.284496736f +
               t * (1.421413741f +
               t * (-1.453152027f +
               t * 1.061405429f))));
    float e = 1.0f - poly * __expf(-z * z);
    e = copysignf(e, v);
    return 0.5f * v * (1.0f + e);
}

#define SWZ(v, imm) __int_as_float(__builtin_amdgcn_ds_swizzle(__float_as_int(v), (imm)))

struct ScanParams { float wr, wi, c2r, c2i; };

__device__ __forceinline__ ScanParams prep_params(
    const float* __restrict__ log_dt, const float* __restrict__ log_A_real,
    const float* __restrict__ A_imag, const float* __restrict__ B_re,
    const float* __restrict__ B_im, const float* __restrict__ C_re,
    const float* __restrict__ C_im, int h, int n)
{
    const int hn = h * NN + n;
    float dt = __expf(log_dt[h]);
    float Are = -__expf(log_A_real[hn]);
    float Aim = A_imag[hn];
    float em = __expf(dt * Are);
    float wr = em * cosf(dt * Aim);
    float wi = em * sinf(dt * Aim);
    float Br = B_re[hn], Bi = B_im[hn];
    float Cr = C_re[hn], Ci = C_im[hn];
    float CBr = Cr * Br - Ci * Bi;
    float CBi = Cr * Bi + Ci * Br;
    float e1r = wr - 1.0f, e1i = wi;
    float numr = CBr * e1r - CBi * e1i;
    float numi = CBr * e1i + CBi * e1r;
    float inv = 1.0f / (Are * Are + Aim * Aim);
    ScanParams P;
    P.wr = wr; P.wi = wi;
    P.c2r = 2.0f * (numr * Are + numi * Aim) * inv;
    P.c2i = 2.0f * (numi * Are - numr * Aim) * inv;
    return P;
}

// Full chunk: broadcast + 32 state steps + output reduce-scatter.
__device__ __forceinline__ float ssm_chunk(float u, int lane, const ScanParams P,
                                           float& sr, float& si,
                                           float* __restrict__ ldsRow)
{
    ldsRow[lane] = u;
    float xs[CHUNK];
    const float4* q4 = (const float4*)ldsRow;
#pragma unroll
    for (int k = 0; k < 8; ++k) {
        float4 v4 = q4[k];
        xs[4 * k + 0] = v4.x;
        xs[4 * k + 1] = v4.y;
        xs[4 * k + 2] = v4.z;
        xs[4 * k + 3] = v4.w;
    }
    float p[CHUNK];
#pragma unroll
    for (int t = 0; t < CHUNK; ++t) {
        float t1 = __fmaf_rn(-P.wi, si, xs[t]);
        float nsr = __fmaf_rn(P.wr, sr, t1);
        float nsi = __fmaf_rn(P.wi, sr, P.wr * si);
        sr = nsr;
        si = nsi;
        p[t] = __fmaf_rn(P.c2r, sr, -(P.c2i * si));
    }
#define BFLY(d, IMM)                                                  \
    {                                                                 \
        bool up = (lane & (d)) != 0;                                  \
        _Pragma("unroll")                                             \
        for (int j = 0; j < (d); ++j) {                               \
            float send = up ? p[j] : p[j + (d)];                      \
            float recv = SWZ(send, (IMM));                            \
            float keep = up ? p[j + (d)] : p[j];                      \
            p[j] = keep + recv;                                       \
        }                                                             \
    }
    BFLY(16, (16 << 10) | 0x1f)
    BFLY(8,  (8  << 10) | 0x1f)
    BFLY(4,  (4  << 10) | 0x1f)
    BFLY(2,  (2  << 10) | 0x1f)
    BFLY(1,  (1  << 10) | 0x1f)
#undef BFLY
    return p[0];
}

// ---------- Phase A: per-segment zero-init carry (state only, no outputs) ----
// grid: bc*24 blocks x 256 = bc*192 groups = bc*32*NSEG. group -> (b,h,seg).
template <int LAYER>
__global__ __launch_bounds__(256) void carry_kernel(
    const float* in, const float* __restrict__ W1, const float* __restrict__ b1,
    const float* __restrict__ log_dt, const float* __restrict__ log_A_real,
    const float* __restrict__ A_imag, const float* __restrict__ B_re,
    const float* __restrict__ B_im, const float* __restrict__ C_re,
    const float* __restrict__ C_im,
    float2* __restrict__ carry)
{
    __shared__ __align__(16) float ldsU[8][CHUNK];
    const int lane = threadIdx.x & 31;
    const int g = threadIdx.x >> 5;
    const int grp = blockIdx.x * 8 + g;
    const int seg = grp % NSEG;
    const int bh = grp / NSEG;        // b*HH + h (local batch)
    const int h = bh & 31;

    const ScanParams P = prep_params(log_dt, log_A_real, A_imag, B_re, B_im, C_re, C_im, h, lane);
    float w1h = 0.f, b1h = 0.f;
    if constexpr (LAYER == 1) { w1h = W1[h]; b1h = b1[h]; }

    const float* src;
    if constexpr (LAYER == 1) src = in + (size_t)(bh >> 5) * LL;
    else                      src = in + (size_t)bh * LL;
    src += seg * SEGLEN;

    float sr = 0.f, si = 0.f;
    for (int c = 0; c < SEGCHUNKS; ++c) {
        float v = src[c * CHUNK + lane];
        float u;
        if constexpr (LAYER == 1) {
            float xl = 6.020599913f * __log2f(fmaxf(fabsf(v), 1e-4f));
            u = fast_gelu(__fmaf_rn(xl, w1h, b1h));
        } else {
            u = v;
        }
        ldsU[g][lane] = u;
        const float4* q4 = (const float4*)ldsU[g];
#pragma unroll
        for (int k = 0; k < 8; ++k) {
            float4 v4 = q4[k];
            float xv[4] = {v4.x, v4.y, v4.z, v4.w};
#pragma unroll
            for (int j = 0; j < 4; ++j) {
                float t1 = __fmaf_rn(-P.wi, si, xv[j]);
                float nsr = __fmaf_rn(P.wr, sr, t1);
                float nsi = __fmaf_rn(P.wi, sr, P.wr * si);
                sr = nsr;
                si = nsi;
            }
        }
    }
    carry[(size_t)(bh * NSEG + seg) * 32 + lane] = make_float2(sr, si);
}

// ---------- Phase B: sequential combine of NSEG carries -> init states -------
// One thread per (b,h,n); grid = bc*4 blocks x 256 (exact). In-place on carry.
__global__ __launch_bounds__(256) void prefix_kernel(
    const float* __restrict__ log_dt, const float* __restrict__ log_A_real,
    const float* __restrict__ A_imag, float2* __restrict__ carry)
{
    const int tid = blockIdx.x * 256 + threadIdx.x; // bc*1024 threads
    const int n = tid & 31;
    const int bh = tid >> 5;
    const int h = bh & 31;

    float dt = __expf(log_dt[h]);
    float Are = -__expf(log_A_real[h * NN + n]);
    float Aim = A_imag[h * NN + n];
    float dr = dt * Are, di = dt * Aim;
    // w^SEGLEN in double for phase accuracy (theta up to ~4e4 rad)
    double th = (double)SEGLEN * (double)di;
    th = fmod(th, 6.283185307179586);
    float em = (float)exp((double)SEGLEN * (double)dr);
    float wLr = em * cosf((float)th);
    float wLi = em * sinf((float)th);

    float rr = 0.f, ri = 0.f;
    float2* base = carry + (size_t)bh * NSEG * 32 + n;
#pragma unroll
    for (int s = 0; s < NSEG; ++s) {
        float2 c = base[(size_t)s * 32];
        base[(size_t)s * 32] = make_float2(rr, ri); // init state for segment s
        float nrr = __fmaf_rn(wLr, rr, __fmaf_rn(-wLi, ri, c.x));
        float nri = __fmaf_rn(wLr, ri, __fmaf_rn(wLi, rr, c.y));
        rr = nrr; ri = nri;
    }
}

// ---------- Phase C: full scan per segment with init state -------------------
template <int LAYER>
__global__ __launch_bounds__(256) void scan_kernel(
    const float* in, const float* __restrict__ W1, const float* __restrict__ b1,
    const float* __restrict__ log_dt, const float* __restrict__ log_A_real,
    const float* __restrict__ A_imag, const float* __restrict__ B_re,
    const float* __restrict__ B_im, const float* __restrict__ C_re,
    const float* __restrict__ C_im, const float* __restrict__ Dp,
    const float2* __restrict__ carry, float* out)
{
    __shared__ __align__(16) float ldsU[8][CHUNK];
    const int lane = threadIdx.x & 31;
    const int g = threadIdx.x >> 5;
    const int grp = blockIdx.x * 8 + g;
    const int seg = grp % NSEG;
    const int bh = grp / NSEG;
    const int h = bh & 31;

    const ScanParams P = prep_params(log_dt, log_A_real, A_imag, B_re, B_im, C_re, C_im, h, lane);
    float Dh = Dp[h];
    float w1h = 0.f, b1h = 0.f;
    if constexpr (LAYER == 1) { w1h = W1[h]; b1h = b1[h]; }

    const float* src;
    if constexpr (LAYER == 1) src = in + (size_t)(bh >> 5) * LL;
    else                      src = in + (size_t)bh * LL;
    src += seg * SEGLEN;
    float* dst = out + (size_t)bh * LL + seg * SEGLEN;

    float2 ini = carry[(size_t)(bh * NSEG + seg) * 32 + lane];
    float sr = ini.x, si = ini.y;

    for (int c = 0; c < SEGCHUNKS; ++c) {
        const int t0 = c * CHUNK;
        float v = src[t0 + lane];
        float u;
        if constexpr (LAYER == 1) {
            float xl = 6.020599913f * __log2f(fmaxf(fabsf(v), 1e-4f));
            u = fast_gelu(__fmaf_rn(xl, w1h, b1h));
        } else {
            u = v;
        }
        float p0 = ssm_chunk(u, lane, P, sr, si, ldsU[g]);
        dst[t0 + lane] = fast_gelu(__fmaf_rn(Dh, u, p0));
    }
}

__global__ __launch_bounds__(256) void mix_kernel(
    const float* g1, const float* __restrict__ W2,
    const float* __restrict__ b2, float* u2)
{
    const int b = blockIdx.y;
    const int l = blockIdx.x * 256 + threadIdx.x;
    if (l >= LL) return;
    float r[HH];
#pragma unroll
    for (int h2 = 0; h2 < HH; ++h2)
        r[h2] = g1[((size_t)b * HH + h2) * LL + l];
#pragma unroll
    for (int h = 0; h < HH; ++h) {
        float acc = b2[h];
#pragma unroll
        for (int h2 = 0; h2 < HH; ++h2)
            acc = __fmaf_rn(r[h2], W2[h2 * HH + h], acc);
        u2[((size_t)b * HH + h) * LL + l] = fast_gelu(acc);
    }
}

__global__ __launch_bounds__(256) void final_kernel(
    const float* __restrict__ g2, const float* __restrict__ W3,
    const float* __restrict__ b3, float* __restrict__ outp)
{
    const int b = blockIdx.y;
    const int l = blockIdx.x * 256 + threadIdx.x;
    if (l >= LL) return;
    float acc = b3[0];
#pragma unroll
    for (int h = 0; h < HH; ++h)
        acc = __fmaf_rn(g2[((size_t)b * HH + h) * LL + l], W3[h], acc);
    outp[(size_t)b * LL + l] = exp2f(acc * 0.16609640474436813f);
}

// ---------------- Path B: fused per-batch kernel (zero workspace) ------------
__global__ __launch_bounds__(1024) void fused_kernel(
    const float* __restrict__ x,
    const float* __restrict__ W1, const float* __restrict__ b1,
    const float* __restrict__ W2, const float* __restrict__ b2,
    const float* __restrict__ W3, const float* __restrict__ b3,
    const float* __restrict__ log_dt1, const float* __restrict__ log_A_real1,
    const float* __restrict__ A_imag1, const float* __restrict__ B_re1,
    const float* __restrict__ B_im1, const float* __restrict__ C_re1,
    const float* __restrict__ C_im1, const float* __restrict__ D1,
    const float* __restrict__ log_dt2, const float* __restrict__ log_A_real2,
    const float* __restrict__ A_imag2, const float* __restrict__ B_re2,
    const float* __restrict__ B_im2, const float* __restrict__ C_re2,
    const float* __restrict__ C_im2, const float* __restrict__ D2,
    float* __restrict__ outp)
{
    __shared__ float ldsA[HH * CHUNK];
    __shared__ float ldsB[HH * CHUNK];
    __shared__ float ldsW2[HH * HH];
    __shared__ __align__(16) float ldsU[HH][CHUNK];

    const int tid = threadIdx.x;
    const int lane = tid & 31;
    const int h = tid >> 5;
    const int b = blockIdx.x;

    ldsW2[tid] = W2[tid];

    const ScanParams P1 = prep_params(log_dt1, log_A_real1, A_imag1, B_re1, B_im1, C_re1, C_im1, h, lane);
    const ScanParams P2 = prep_params(log_dt2, log_A_real2, A_imag2, B_re2, B_im2, C_re2, C_im2, h, lane);
    const float w1h = W1[h], b1h = b1[h];
    const float Dh1 = D1[h], Dh2 = D2[h];
    const float b2h = b2[h];
    const float b30 = b3[0];
    float w3r[HH];
#pragma unroll
    for (int hh = 0; hh < HH; ++hh) w3r[hh] = W3[hh];

    const float* src = x + (size_t)b * LL;
    float* dst = outp + (size_t)b * LL;

    float sr1 = 0.f, si1 = 0.f, sr2 = 0.f, si2 = 0.f;

    for (int c = 0; c < NCHUNK; ++c) {
        const int t0 = c * CHUNK;
        float v = src[t0 + lane];
        float xl = 6.020599913f * __log2f(fmaxf(fabsf(v), 1e-4f));
        float u1 = fast_gelu(__fmaf_rn(xl, w1h, b1h));
        float p0 = ssm_chunk(u1, lane, P1, sr1, si1, ldsU[h]);
        float g1v = fast_gelu(__fmaf_rn(Dh1, u1, p0));
        ldsA[(h << 5) | lane] = g1v;
        __syncthreads();
        float acc = b2h;
#pragma unroll
        for (int h2 = 0; h2 < HH; ++h2)
            acc = __fmaf_rn(ldsA[(h2 << 5) | lane], ldsW2[(h2 << 5) | h], acc);
        float u2 = fast_gelu(acc);
        float q0 = ssm_chunk(u2, lane, P2, sr2, si2, ldsU[h]);
        float g2v = fast_gelu(__fmaf_rn(Dh2, u2, q0));
        ldsB[(h << 5) | lane] = g2v;
        __syncthreads();
        if (h == 0) {
            float a = b30;
#pragma unroll
            for (int hh = 0; hh < HH; ++hh)
                a = __fmaf_rn(ldsB[(hh << 5) | lane], w3r[hh], a);
            dst[t0 + lane] = exp2f(a * 0.16609640474436813f);
        }
    }
}

extern "C" void kernel_launch(void* const* d_in, const int* in_sizes, int n_in,
                              void* d_out, int out_size, void* d_ws, size_t ws_size,
                              hipStream_t stream)
{
    const float* x  = (const float*)d_in[0];
    const float* W1 = (const float*)d_in[1];
    const float* b1 = (const float*)d_in[2];
    const float* W2 = (const float*)d_in[3];
    const float* b2 = (const float*)d_in[4];
    const float* W3 = (const float*)d_in[5];
    const float* b3 = (const float*)d_in[6];
    const float* p1[8];
    const float* p2[8];
    for (int i = 0; i < 8; ++i) p1[i] = (const float*)d_in[7 + i];
    for (int i = 0; i < 8; ++i) p2[i] = (const float*)d_in[15 + i];
    float* outp = (float*)d_out;

    const size_t per_batch = (size_t)HH * LL * sizeof(float);            // 3,072,000 B
    const size_t carry_bytes = (size_t)BB * HH * NSEG * NN * sizeof(float2); // 6,291,456 B

    int bchunk = 0;
    if (ws_size > carry_bytes + per_batch) {
        size_t av = (ws_size - carry_bytes) / per_batch;
        bchunk = av > BB ? BB : (int)av;
    }

    if (bchunk >= 8) {
        float* buf = (float*)d_ws;                               // [bchunk,H,L] f32
        float2* carry = (float2*)((char*)d_ws + per_batch * (size_t)bchunk);
        for (int b0 = 0; b0 < BB; b0 += bchunk) {
            int bc = (BB - b0) < bchunk ? (BB - b0) : bchunk;
            dim3 cgrid(bc * 24), blk(256);                       // bc*32*NSEG/8
            dim3 pgrid(bc * 4);
            dim3 egrid((LL + 255) / 256, bc);
            carry_kernel<1><<<cgrid, blk, 0, stream>>>(
                x + (size_t)b0 * LL, W1, b1,
                p1[0], p1[1], p1[2], p1[3], p1[4], p1[5], p1[6], carry);
            prefix_kernel<<<pgrid, blk, 0, stream>>>(p1[0], p1[1], p1[2], carry);
            scan_kernel<1><<<cgrid, blk, 0, stream>>>(
                x + (size_t)b0 * LL, W1, b1,
                p1[0], p1[1], p1[2], p1[3], p1[4], p1[5], p1[6], p1[7], carry, buf);
            mix_kernel<<<egrid, blk, 0, stream>>>(buf, W2, b2, buf);
            carry_kernel<2><<<cgrid, blk, 0, stream>>>(
                buf, nullptr, nullptr,
                p2[0], p2[1], p2[2], p2[3], p2[4], p2[5], p2[6], carry);
            prefix_kernel<<<pgrid, blk, 0, stream>>>(p2[0], p2[1], p2[2], carry);
            scan_kernel<2><<<cgrid, blk, 0, stream>>>(
                buf, nullptr, nullptr,
                p2[0], p2[1], p2[2], p2[3], p2[4], p2[5], p2[6], p2[7], carry, buf);
            final_kernel<<<egrid, blk, 0, stream>>>(
                buf, W3, b3, outp + (size_t)b0 * LL);
        }
    } else {
        fused_kernel<<<dim3(BB), dim3(1024), 0, stream>>>(
            x, W1, b1, W2, b2, W3, b3,
            p1[0], p1[1], p1[2], p1[3], p1[4], p1[5], p1[6], p1[7],
            p2[0], p2[1], p2[2], p2[3], p2[4], p2[5], p2[6], p2[7],
            outp);
    }
}